// Round 11
// baseline (29.451 us; speedup 1.0000x reference)
//
#include <hip/hip_runtime.h>
#include <stdint.h>

#define BATCH 16384
#define KDIM  512
#define NDIM  1024
#define NW    16            // 512 bits = 16 uint32 words per row
#define THREADS 256         // 4 waves; wave w owns column strip [256w, 256w+256)
#define ROWS_PER_BLOCK 16   // 1024 blocks (4/CU)

typedef int i32x4 __attribute__((ext_vector_type(4)));

// --- G packing (UNCHANGED — verified rounds 2-10): 512 blocks, 8 threads
// per word (4 bits each), LDS combine. Bit c of word (m,n) is
// G[kbase(m) + 4c, n], kbase = 256*(m>>3) + 128*((m>>2)&1) + (m&3).
__global__ __launch_bounds__(256) void pack_g_kernel(const float* __restrict__ G,
                                                     uint32_t* __restrict__ Gt) {
    __shared__ uint32_t nib[8][32];
    const int bid = blockIdx.x;          // 512 blocks
    const int m   = bid >> 5;            // 0..15
    const int n0  = (bid & 31) << 5;     // column chunk base
    const int tid = threadIdx.x;
    const int p   = tid >> 5;            // piece 0..7 (bits 4p..4p+3)
    const int nn  = tid & 31;
    const int kbase = 256 * (m >> 3) + 128 * ((m >> 2) & 1) + (m & 3);
    uint32_t w = 0;
#pragma unroll
    for (int j = 0; j < 4; ++j) {
        int c = 4 * p + j;
        w |= (uint32_t)(G[(size_t)(kbase + 4 * c) * NDIM + n0 + nn] > 0.5f) << c;
    }
    nib[p][nn] = w;
    __syncthreads();
    if (tid < 32) {
        uint32_t r = nib[0][tid] | nib[1][tid] | nib[2][tid] | nib[3][tid]
                   | nib[4][tid] | nib[5][tid] | nib[6][tid] | nib[7][tid];
        Gt[m * NDIM + n0 + tid] = r;
    }
}

// --- fused GF(2) GEMM, wave-autonomous: NO LDS, NO barriers ---
// Each WAVE reads a full x row itself (lane l: float4 at col 4l and 256+4l),
// ballots it into 16 wave-uniform SGPR words, and computes 4 output columns
// per lane (colbase = 256*wave + 4*lane) via AND(sgpr,g)+XOR tree + popc.
// Ballot word m = h*8 + hb*4 + j has bit c = x[row, 256h + 128hb + 4c + j]
// == the verified Gt layout. 4 waves/block ballot the same rows (redundant
// reads served by L1/L2; HBM x traffic stays 32 MB). Stores: int4, 1 KB/wave.
__global__ __launch_bounds__(THREADS, 4)
void gf2_fused_kernel(const float* __restrict__ x,
                      const uint32_t* __restrict__ Gt,
                      int* __restrict__ out) {
    const int tid = threadIdx.x;
    const int w   = tid >> 6;     // wave 0..3 -> column strip
    const int l   = tid & 63;     // lane
    const int row0 = blockIdx.x * ROWS_PER_BLOCK;
    const int colbase = w * 256 + 4 * l;

    // persistent column fragments: cols colbase..colbase+3 (uint4 loads)
    uint32_t g0[NW], g1[NW], g2[NW], g3[NW];
#pragma unroll
    for (int m = 0; m < NW; ++m) {
        uint4 gg = *reinterpret_cast<const uint4*>(Gt + m * NDIM + colbase);
        g0[m] = gg.x;
        g1[m] = gg.y;
        g2[m] = gg.z;
        g3[m] = gg.w;
    }

    const float4* xf = reinterpret_cast<const float4*>(x);

    // software-pipelined row loop: prefetch row r+1 while computing row r
    float4 fA = xf[(size_t)row0 * (KDIM / 4) + l];        // cols 4l..4l+3
    float4 fB = xf[(size_t)row0 * (KDIM / 4) + 64 + l];   // cols 256+4l..+3

#pragma unroll 2
    for (int r = 0; r < ROWS_PER_BLOCK; ++r) {
        // ballot-pack the row: 16 wave-uniform words in SGPRs
        uint64_t bA0 = __ballot(fA.x > 0.5f);
        uint64_t bA1 = __ballot(fA.y > 0.5f);
        uint64_t bA2 = __ballot(fA.z > 0.5f);
        uint64_t bA3 = __ballot(fA.w > 0.5f);
        uint64_t bB0 = __ballot(fB.x > 0.5f);
        uint64_t bB1 = __ballot(fB.y > 0.5f);
        uint64_t bB2 = __ballot(fB.z > 0.5f);
        uint64_t bB3 = __ballot(fB.w > 0.5f);

        if (r + 1 < ROWS_PER_BLOCK) {
            fA = xf[(size_t)(row0 + r + 1) * (KDIM / 4) + l];
            fB = xf[(size_t)(row0 + r + 1) * (KDIM / 4) + 64 + l];
        }

        // words m=0..15: {lo(bA_j)}, {hi(bA_j)}, {lo(bB_j)}, {hi(bB_j)}
        uint32_t m0  = (uint32_t)bA0,  m1  = (uint32_t)bA1;
        uint32_t m2  = (uint32_t)bA2,  m3  = (uint32_t)bA3;
        uint32_t m4  = (uint32_t)(bA0 >> 32), m5  = (uint32_t)(bA1 >> 32);
        uint32_t m6  = (uint32_t)(bA2 >> 32), m7  = (uint32_t)(bA3 >> 32);
        uint32_t m8  = (uint32_t)bB0,  m9  = (uint32_t)bB1;
        uint32_t m10 = (uint32_t)bB2,  m11 = (uint32_t)bB3;
        uint32_t m12 = (uint32_t)(bB0 >> 32), m13 = (uint32_t)(bB1 >> 32);
        uint32_t m14 = (uint32_t)(bB2 >> 32), m15 = (uint32_t)(bB3 >> 32);

        uint32_t t0 = (m0 & g0[0])   ^ (m1 & g0[1])   ^ (m2 & g0[2])   ^ (m3 & g0[3])
                    ^ (m4 & g0[4])   ^ (m5 & g0[5])   ^ (m6 & g0[6])   ^ (m7 & g0[7])
                    ^ (m8 & g0[8])   ^ (m9 & g0[9])   ^ (m10 & g0[10]) ^ (m11 & g0[11])
                    ^ (m12 & g0[12]) ^ (m13 & g0[13]) ^ (m14 & g0[14]) ^ (m15 & g0[15]);
        uint32_t t1 = (m0 & g1[0])   ^ (m1 & g1[1])   ^ (m2 & g1[2])   ^ (m3 & g1[3])
                    ^ (m4 & g1[4])   ^ (m5 & g1[5])   ^ (m6 & g1[6])   ^ (m7 & g1[7])
                    ^ (m8 & g1[8])   ^ (m9 & g1[9])   ^ (m10 & g1[10]) ^ (m11 & g1[11])
                    ^ (m12 & g1[12]) ^ (m13 & g1[13]) ^ (m14 & g1[14]) ^ (m15 & g1[15]);
        uint32_t t2 = (m0 & g2[0])   ^ (m1 & g2[1])   ^ (m2 & g2[2])   ^ (m3 & g2[3])
                    ^ (m4 & g2[4])   ^ (m5 & g2[5])   ^ (m6 & g2[6])   ^ (m7 & g2[7])
                    ^ (m8 & g2[8])   ^ (m9 & g2[9])   ^ (m10 & g2[10]) ^ (m11 & g2[11])
                    ^ (m12 & g2[12]) ^ (m13 & g2[13]) ^ (m14 & g2[14]) ^ (m15 & g2[15]);
        uint32_t t3 = (m0 & g3[0])   ^ (m1 & g3[1])   ^ (m2 & g3[2])   ^ (m3 & g3[3])
                    ^ (m4 & g3[4])   ^ (m5 & g3[5])   ^ (m6 & g3[6])   ^ (m7 & g3[7])
                    ^ (m8 & g3[8])   ^ (m9 & g3[9])   ^ (m10 & g3[10]) ^ (m11 & g3[11])
                    ^ (m12 & g3[12]) ^ (m13 & g3[13]) ^ (m14 & g3[14]) ^ (m15 & g3[15]);

        i32x4 o;
        o.x = (int)(__popc(t0) & 1u);
        o.y = (int)(__popc(t1) & 1u);
        o.z = (int)(__popc(t2) & 1u);
        o.w = (int)(__popc(t3) & 1u);
        *reinterpret_cast<i32x4*>(out + (size_t)(row0 + r) * NDIM + colbase) = o;
    }
}

extern "C" void kernel_launch(void* const* d_in, const int* in_sizes, int n_in,
                              void* d_out, int out_size, void* d_ws, size_t ws_size,
                              hipStream_t stream) {
    const float* x = (const float*)d_in[0];   // [BATCH, KDIM] float32 (0/1)
    const float* G = (const float*)d_in[1];   // [KDIM, NDIM] float32 (0/1)
    int* out = (int*)d_out;                   // [BATCH, NDIM] int32

    uint32_t* Gt = (uint32_t*)d_ws;           // 64 KiB packed G

    pack_g_kernel<<<512, 256, 0, stream>>>(G, Gt);
    gf2_fused_kernel<<<BATCH / ROWS_PER_BLOCK, THREADS, 0, stream>>>(x, Gt, out);
}